// Round 5
// baseline (248.116 us; speedup 1.0000x reference)
//
#include <hip/hip_runtime.h>

// EnhancedReconstructionLoss: loss = 0.8*mean((x-y)^2) + 0.2*(1 - mean(ssim_map))
// ssim from 3x3 avg pools (stride 1, zero-pad 1, divisor always 9).
// Shapes: (32,3,512,512) fp32 -> 96 planes of 512x512.
//
// R2: atomics -> per-block partial stores (639 -> 101 us main).
// R3: parallel 2-stage reduce; rcp instead of divide (96 us main).
// R4: 64x64 LDS tile, 16 px/thread: VALU halved but 40KB LDS -> 3 blocks/CU
//     (Occupancy 37%) -> latency-bound, only -5us. Wrong resource trade.
// R5: registers-only streaming. One wave = 256-wide x 16-row band (4 cols/lane,
//     float4 loads). Vertical reuse = rolling h-partials in regs; horizontal
//     +-1 via __shfl; inner strip edge via 2 predicated dword loads/row; plane
//     edges zero (= zero-pad). No LDS, no barriers in hot path.

#define PLANE_ELEMS (512 * 512)
#define BH      16                         // output rows per wave
#define NWAVES  (96 * 32 * 2)              // planes x bands x strips = 6144
#define NBLOCKS (NWAVES / 4)               // 1536
#define NB1     (NBLOCKS / 256)            // 6

static constexpr float kC1s  = 81.0f * 0.0001f;   // 81*C1
static constexpr float kC2s  = 81.0f * 0.0009f;   // 81*C2
static constexpr float kEPSs = 6561.0f * 1e-8f;   // 81^2*eps
static constexpr float kINVN = 1.0f / 25165824.0f;

__global__ __launch_bounds__(256) void loss_stream(
    const float* __restrict__ X, const float* __restrict__ Y,
    float* __restrict__ part)
{
    const int tid   = threadIdx.x;
    const int lane  = tid & 63;
    const int wid   = blockIdx.x * 4 + (tid >> 6);
    const int plane = wid >> 6;            // 64 waves per plane
    const int rem   = wid & 63;
    const int band  = rem >> 1;            // 0..31
    const int strip = rem & 1;             // 0..1
    const int rb    = band << 4;           // first output row
    const int c0    = (strip << 8) + (lane << 2);   // first of 4 columns

    const float* __restrict__ xp = X + (size_t)plane * PLANE_ELEMS;
    const float* __restrict__ yp = Y + (size_t)plane * PLANE_ELEMS;

    const bool leftEdge  = (lane == 0)  && (strip == 1);   // needs col 255
    const bool rightEdge = (lane == 63) && (strip == 0);   // needs col 256

    float h0[5][4], h1[5][4], xm[4], ym[4];
    float mse_acc = 0.0f, ssim_acc = 0.0f;

    // Process one input row: produce 5 horizontal 3-tap partials for 4 columns.
    auto hrow = [&](int rr, float (&hc)[5][4], float4& vx, float4& vy) {
        const int  r  = rb - 1 + rr;
        const bool rv = ((unsigned)r < 512u);    // wave-uniform
        vx = make_float4(0.f, 0.f, 0.f, 0.f);
        vy = make_float4(0.f, 0.f, 0.f, 0.f);
        float xl = 0.f, yl = 0.f, xr = 0.f, yr = 0.f;
        if (rv) {
            const float* __restrict__ prx = xp + (size_t)r * 512;
            const float* __restrict__ pry = yp + (size_t)r * 512;
            vx = *(const float4*)(prx + c0);
            vy = *(const float4*)(pry + c0);
            if (leftEdge)  { xl = prx[255]; yl = pry[255]; }
            if (rightEdge) { xr = prx[256]; yr = pry[256]; }
        }
        // horizontal +-1 from neighbor lanes (lane 0 / 63 keep edge values)
        const float sxl = __shfl_up(vx.w, 1);
        const float syl = __shfl_up(vy.w, 1);
        const float sxr = __shfl_down(vx.x, 1);
        const float syr = __shfl_down(vy.x, 1);
        if (lane != 0)  { xl = sxl; yl = syl; }
        if (lane != 63) { xr = sxr; yr = syr; }

        const float ex[6] = {xl, vx.x, vx.y, vx.z, vx.w, xr};
        const float ey[6] = {yl, vy.x, vy.y, vy.z, vy.w, yr};
        float xx[6], yy[6], xy[6];
#pragma unroll
        for (int m = 0; m < 6; ++m) {
            xx[m] = ex[m] * ex[m];
            yy[m] = ey[m] * ey[m];
            xy[m] = ex[m] * ey[m];
        }
#pragma unroll
        for (int q = 0; q < 4; ++q) {
            hc[0][q] = ex[q] + ex[q + 1] + ex[q + 2];
            hc[1][q] = ey[q] + ey[q + 1] + ey[q + 2];
            hc[2][q] = xx[q] + xx[q + 1] + xx[q + 2];
            hc[3][q] = yy[q] + yy[q + 1] + yy[q + 2];
            hc[4][q] = xy[q] + xy[q + 1] + xy[q + 2];
        }
    };

    float4 vx, vy;
    hrow(0, h0, vx, vy);                       // row rb-1
    hrow(1, h1, vx, vy);                       // row rb
    xm[0] = vx.x; xm[1] = vx.y; xm[2] = vx.z; xm[3] = vx.w;
    ym[0] = vy.x; ym[1] = vy.y; ym[2] = vy.z; ym[3] = vy.w;

#pragma unroll
    for (int rr = 2; rr < BH + 2; ++rr) {
        float hc[5][4];
        hrow(rr, hc, vx, vy);                  // row rb-1+rr

        // emit output row rb + rr - 2 (center row values are in xm/ym)
#pragma unroll
        for (int q = 0; q < 4; ++q) {
            const float s_x  = h0[0][q] + h1[0][q] + hc[0][q];
            const float s_y  = h0[1][q] + h1[1][q] + hc[1][q];
            const float s_xx = h0[2][q] + h1[2][q] + hc[2][q];
            const float s_yy = h0[3][q] + h1[3][q] + hc[3][q];
            const float s_xy = h0[4][q] + h1[4][q] + hc[4][q];

            // scaled-domain SSIM (everything x81; ratio unchanged up to eps scale)
            const float P   = s_x * s_y;
            const float Q   = s_x * s_x + s_y * s_y;
            const float t1  = 2.0f * P + kC1s;
            const float t3  = 2.0f * (9.0f * s_xy - P) + kC2s;
            const float num = t1 * t3;
            const float u1  = Q + kC1s;
            const float u2  = 9.0f * (s_xx + s_yy) - Q;    // >= 0 (Cauchy-Schwarz)
            const float den = u1 * (u2 + kC2s) + kEPSs;    // > 0 always
            ssim_acc += num * __builtin_amdgcn_rcpf(den);

            const float d = xm[q] - ym[q];
            mse_acc += d * d;
        }

        // rotate rolling state (renamed away under full unroll)
#pragma unroll
        for (int t = 0; t < 5; ++t)
#pragma unroll
            for (int q = 0; q < 4; ++q) {
                h0[t][q] = h1[t][q];
                h1[t][q] = hc[t][q];
            }
        xm[0] = vx.x; xm[1] = vx.y; xm[2] = vx.z; xm[3] = vx.w;
        ym[0] = vy.x; ym[1] = vy.y; ym[2] = vy.z; ym[3] = vy.w;
    }

    // ---- block reduction (4 waves) ----
#pragma unroll
    for (int off = 32; off > 0; off >>= 1) {
        mse_acc  += __shfl_down(mse_acc, off, 64);
        ssim_acc += __shfl_down(ssim_acc, off, 64);
    }
    __shared__ float red[8];
    const int wave = tid >> 6;
    if ((tid & 63) == 0) {
        red[wave]     = mse_acc;
        red[4 + wave] = ssim_acc;
    }
    __syncthreads();
    if (tid == 0) {
        part[blockIdx.x]           = red[0] + red[1] + red[2] + red[3];
        part[NBLOCKS + blockIdx.x] = red[4] + red[5] + red[6] + red[7];
    }
}

__global__ __launch_bounds__(256) void loss_reduce1(
    const float* __restrict__ part, float* __restrict__ part2)
{
    const int tid = threadIdx.x;
    const int i   = blockIdx.x * 256 + tid;
    float m = part[i];
    float s = part[NBLOCKS + i];
#pragma unroll
    for (int off = 32; off > 0; off >>= 1) {
        m += __shfl_down(m, off, 64);
        s += __shfl_down(s, off, 64);
    }
    __shared__ float red[8];
    const int wave = tid >> 6;
    if ((tid & 63) == 0) {
        red[wave]     = m;
        red[4 + wave] = s;
    }
    __syncthreads();
    if (tid == 0) {
        part2[blockIdx.x]       = red[0] + red[1] + red[2] + red[3];
        part2[NB1 + blockIdx.x] = red[4] + red[5] + red[6] + red[7];
    }
}

__global__ __launch_bounds__(64) void loss_final(
    const float* __restrict__ part2, float* __restrict__ out)
{
    const int tid = threadIdx.x;
    float m = 0.0f, s = 0.0f;
    if (tid < NB1) {
        m = part2[tid];
        s = part2[NB1 + tid];
    }
#pragma unroll
    for (int off = 32; off > 0; off >>= 1) {
        m += __shfl_down(m, off, 64);
        s += __shfl_down(s, off, 64);
    }
    if (tid == 0) {
        const float mse       = m * kINVN;
        const float ssim_mean = s * kINVN;
        out[0] = 0.8f * mse + 0.2f * (1.0f - ssim_mean);
    }
}

extern "C" void kernel_launch(void* const* d_in, const int* in_sizes, int n_in,
                              void* d_out, int out_size, void* d_ws, size_t ws_size,
                              hipStream_t stream)
{
    const float* x = (const float*)d_in[0];   // reconstruction
    const float* y = (const float*)d_in[1];   // target
    float* out   = (float*)d_out;
    float* part  = (float*)d_ws;              // 2*NBLOCKS floats
    float* part2 = part + 2 * NBLOCKS;        // 2*NB1 floats

    loss_stream<<<NBLOCKS, 256, 0, stream>>>(x, y, part);
    loss_reduce1<<<NB1, 256, 0, stream>>>(part, part2);
    loss_final<<<1, 64, 0, stream>>>(part2, out);
}

// Round 7
// 225.819 us; speedup vs baseline: 1.0987x; 1.0987x over previous
//
#include <hip/hip_runtime.h>

// EnhancedReconstructionLoss: loss = 0.8*mean((x-y)^2) + 0.2*(1 - mean(ssim_map))
// ssim from 3x3 avg pools (stride 1, zero-pad 1, divisor always 9).
// Shapes: (32,3,512,512) fp32 -> 96 planes of 512x512.
//
// R2: atomics -> per-block partial stores (639 -> 101 us main).
// R3: parallel 2-stage reduce; rcp not divide (96 us; 79% occ, VALU-bound).
// R4: 64x64 f32 LDS tile, 4x4/thread (91 us; 27.7 inst/px but 40KB LDS ->
//     12 waves/CU, latency-bound).
// R5: no-LDS register streaming (108 us; VGPR 164 -> 10.7% occ. Worse).
// R6: f16 LDS staging (19 KB/block -> 8 blocks/CU = 32 waves/CU) + R4's
//     4x4-patch arithmetic. MSE computed during staging from pristine f32
//     (exact). COMPILE FIX R7: cvt_pkrtz returns __fp16 vectors, not
//     _Float16 -> typedef on __fp16.

#define PLANE_H 512
#define PLANE_W 512
#define NPLANES 96
#define TILE    64
#define LDSH    66                  // TILE + 2 halo rows
#define LDSW    72                  // halfs/row: cols tc0-4 .. tc0+67; 144 B stride
#define NQUADS  (LDSH * 18)         // 18 float4-quads per row -> 1188
#define NBLOCKS ((PLANE_W / TILE) * (PLANE_H / TILE) * NPLANES)   // 6144
#define NB1     (NBLOCKS / 256)     // 24

typedef __fp16 half_t;
typedef __fp16 half2_t __attribute__((ext_vector_type(2)));
typedef __fp16 half4_t __attribute__((ext_vector_type(4)));

static constexpr float kC1s  = 81.0f * 0.0001f;   // 81*C1
static constexpr float kC2s  = 81.0f * 0.0009f;   // 81*C2
static constexpr float kEPSs = 6561.0f * 1e-8f;   // 81^2*eps
static constexpr float kINVN = 1.0f / 25165824.0f;

__global__ __launch_bounds__(256, 8) void loss_main(
    const float* __restrict__ X, const float* __restrict__ Y,
    float* __restrict__ part)
{
    __shared__ __align__(16) half_t sxh[LDSH][LDSW];
    __shared__ __align__(16) half_t syh[LDSH][LDSW];

    const int tid   = threadIdx.x;
    const int tr0   = blockIdx.y * TILE;
    const int tc0   = blockIdx.x * TILE;
    const int plane = blockIdx.z;

    const float* __restrict__ xp = X + (size_t)plane * (PLANE_H * PLANE_W);
    const float* __restrict__ yp = Y + (size_t)plane * (PLANE_H * PLANE_W);

    float mse_acc = 0.0f, ssim_acc = 0.0f;

    // ---- stage halo as f16; accumulate exact f32 MSE for interior quads ----
    // quad i -> row hr = i/18, quad-col hq = i%18; global (tr0-1+hr, tc0-4+4*hq).
    // Quads are fully in-plane or fully out (tc0 % 64 == 0), zero-fill = zero-pad.
    for (int i = tid; i < NQUADS; i += 256) {
        const int hr = i / 18;
        const int hq = i - hr * 18;
        const int gr = tr0 - 1 + hr;
        const int gc = tc0 - 4 + 4 * hq;
        float4 vx = make_float4(0.f, 0.f, 0.f, 0.f);
        float4 vy = make_float4(0.f, 0.f, 0.f, 0.f);
        if ((unsigned)gr < PLANE_H && (unsigned)gc < PLANE_W) {
            const size_t g = (size_t)gr * PLANE_W + (size_t)gc;
            vx = *(const float4*)(xp + g);
            vy = *(const float4*)(yp + g);
        }
        // MSE from pristine f32: tile-interior quads only (each pixel once)
        if (hr >= 1 && hr <= TILE && hq >= 1 && hq <= 16) {
            const float d0 = vx.x - vy.x, d1 = vx.y - vy.y;
            const float d2 = vx.z - vy.z, d3 = vx.w - vy.w;
            mse_acc += d0 * d0 + d1 * d1 + d2 * d2 + d3 * d3;
        }
        const half2_t xl = __builtin_amdgcn_cvt_pkrtz(vx.x, vx.y);
        const half2_t xh = __builtin_amdgcn_cvt_pkrtz(vx.z, vx.w);
        const half2_t yl = __builtin_amdgcn_cvt_pkrtz(vy.x, vy.y);
        const half2_t yh = __builtin_amdgcn_cvt_pkrtz(vy.z, vy.w);
        const half4_t x4 = {xl.x, xl.y, xh.x, xh.y};
        const half4_t y4 = {yl.x, yl.y, yh.x, yh.y};
        *(half4_t*)&sxh[hr][4 * hq] = x4;   // 8B-aligned ds_write_b64
        *(half4_t*)&syh[hr][4 * hq] = y4;
    }
    __syncthreads();

    // ---- each thread: 4x4 pixel patch ----
    // pixel (pr, pc) -> LDS (pr+1, pc+4). Need cols pc0-1..pc0+4 = LDS 4q+3..4q+8.
    const int q   = tid & 15;        // thread-col
    const int pr0 = (tid >> 4) * 4;  // first pixel row of patch

    float h0[5][4], h1[5][4];

#pragma unroll
    for (int j = 0; j < 6; ++j) {
        const int R = pr0 + j;       // LDS row

        const half_t* __restrict__ rx = &sxh[R][0];
        const half_t* __restrict__ ry = &syh[R][0];
        const half2_t ax = *(const half2_t*)&rx[4 * q + 2];   // b32
        const half4_t bx = *(const half4_t*)&rx[4 * q + 4];   // b64
        const half2_t cx = *(const half2_t*)&rx[4 * q + 8];   // b32
        const half2_t ay = *(const half2_t*)&ry[4 * q + 2];
        const half4_t by = *(const half4_t*)&ry[4 * q + 4];
        const half2_t cy = *(const half2_t*)&ry[4 * q + 8];

        const float ex[6] = {(float)ax.y, (float)bx.x, (float)bx.y,
                             (float)bx.z, (float)bx.w, (float)cx.x};
        const float ey[6] = {(float)ay.y, (float)by.x, (float)by.y,
                             (float)by.z, (float)by.w, (float)cy.x};

        float xx[6], yy[6], xy[6];
#pragma unroll
        for (int m = 0; m < 6; ++m) {
            xx[m] = ex[m] * ex[m];
            yy[m] = ey[m] * ey[m];
            xy[m] = ex[m] * ey[m];
        }

        float hc[5][4];
#pragma unroll
        for (int c = 0; c < 4; ++c) {
            hc[0][c] = ex[c] + ex[c + 1] + ex[c + 2];
            hc[1][c] = ey[c] + ey[c + 1] + ey[c + 2];
            hc[2][c] = xx[c] + xx[c + 1] + xx[c + 2];
            hc[3][c] = yy[c] + yy[c + 1] + yy[c + 2];
            hc[4][c] = xy[c] + xy[c + 1] + xy[c + 2];
        }

        if (j >= 2) {
#pragma unroll
            for (int c = 0; c < 4; ++c) {
                const float s_x  = h0[0][c] + h1[0][c] + hc[0][c];
                const float s_y  = h0[1][c] + h1[1][c] + hc[1][c];
                const float s_xx = h0[2][c] + h1[2][c] + hc[2][c];
                const float s_yy = h0[3][c] + h1[3][c] + hc[3][c];
                const float s_xy = h0[4][c] + h1[4][c] + hc[4][c];

                // scaled-domain SSIM: all window sums x9 (i.e. mu x9),
                // num/den each carry 81^2 which cancels; eps scales by 81^2.
                const float P   = s_x * s_y;
                const float Q   = s_x * s_x + s_y * s_y;
                const float t1  = 2.0f * P + kC1s;
                const float t3  = 2.0f * (9.0f * s_xy - P) + kC2s;
                const float num = t1 * t3;
                const float u1  = Q + kC1s;
                const float u2  = 9.0f * (s_xx + s_yy) - Q;   // >= 0 (C-S ineq.)
                const float den = u1 * (u2 + kC2s) + kEPSs;   // > 0 always
                ssim_acc += num * __builtin_amdgcn_rcpf(den);
            }
        }

#pragma unroll
        for (int t = 0; t < 5; ++t)
#pragma unroll
            for (int c = 0; c < 4; ++c) {
                h0[t][c] = h1[t][c];
                h1[t][c] = hc[t][c];
            }
    }

    // ---- block reduction ----
#pragma unroll
    for (int off = 32; off > 0; off >>= 1) {
        mse_acc  += __shfl_down(mse_acc, off, 64);
        ssim_acc += __shfl_down(ssim_acc, off, 64);
    }
    __shared__ float red[8];
    const int wave = tid >> 6;
    if ((tid & 63) == 0) {
        red[wave]     = mse_acc;
        red[4 + wave] = ssim_acc;
    }
    __syncthreads();
    if (tid == 0) {
        const int bid = (blockIdx.z * gridDim.y + blockIdx.y) * gridDim.x + blockIdx.x;
        part[bid]           = red[0] + red[1] + red[2] + red[3];
        part[NBLOCKS + bid] = red[4] + red[5] + red[6] + red[7];
    }
}

__global__ __launch_bounds__(256) void loss_reduce1(
    const float* __restrict__ part, float* __restrict__ part2)
{
    const int tid = threadIdx.x;
    const int i   = blockIdx.x * 256 + tid;
    float m = part[i];
    float s = part[NBLOCKS + i];
#pragma unroll
    for (int off = 32; off > 0; off >>= 1) {
        m += __shfl_down(m, off, 64);
        s += __shfl_down(s, off, 64);
    }
    __shared__ float red[8];
    const int wave = tid >> 6;
    if ((tid & 63) == 0) {
        red[wave]     = m;
        red[4 + wave] = s;
    }
    __syncthreads();
    if (tid == 0) {
        part2[blockIdx.x]       = red[0] + red[1] + red[2] + red[3];
        part2[NB1 + blockIdx.x] = red[4] + red[5] + red[6] + red[7];
    }
}

__global__ __launch_bounds__(64) void loss_final(
    const float* __restrict__ part2, float* __restrict__ out)
{
    const int tid = threadIdx.x;
    float m = 0.0f, s = 0.0f;
    if (tid < NB1) {
        m = part2[tid];
        s = part2[NB1 + tid];
    }
#pragma unroll
    for (int off = 32; off > 0; off >>= 1) {
        m += __shfl_down(m, off, 64);
        s += __shfl_down(s, off, 64);
    }
    if (tid == 0) {
        const float mse       = m * kINVN;
        const float ssim_mean = s * kINVN;
        out[0] = 0.8f * mse + 0.2f * (1.0f - ssim_mean);
    }
}

extern "C" void kernel_launch(void* const* d_in, const int* in_sizes, int n_in,
                              void* d_out, int out_size, void* d_ws, size_t ws_size,
                              hipStream_t stream)
{
    const float* x = (const float*)d_in[0];   // reconstruction
    const float* y = (const float*)d_in[1];   // target
    float* out   = (float*)d_out;
    float* part  = (float*)d_ws;              // 2*NBLOCKS floats
    float* part2 = part + 2 * NBLOCKS;        // 2*NB1 floats

    dim3 grid(PLANE_W / TILE, PLANE_H / TILE, NPLANES);   // 8 x 8 x 96 = 6144
    loss_main<<<grid, 256, 0, stream>>>(x, y, part);
    loss_reduce1<<<NB1, 256, 0, stream>>>(part, part2);
    loss_final<<<1, 64, 0, stream>>>(part2, out);
}